// Round 4
// baseline (822.896 us; speedup 1.0000x reference)
//
#include <hip/hip_runtime.h>

typedef short bf16x8 __attribute__((ext_vector_type(8)));
typedef float f32x4 __attribute__((ext_vector_type(4)));
typedef float f32x16 __attribute__((ext_vector_type(16)));

// ---------- helpers ----------
__device__ __forceinline__ ushort f2bf(float f) {
  union { float f; unsigned u; } x; x.f = f;
  unsigned r = x.u + 0x7fffu + ((x.u >> 16) & 1u);  // RNE
  return (ushort)(r >> 16);
}
__device__ __forceinline__ float bf2f(ushort u) {
  union { unsigned u; float f; } x; x.u = ((unsigned)u) << 16; return x.f;
}
__device__ __forceinline__ void load_lds16(const void* g, void* l) {
  __builtin_amdgcn_global_load_lds((const __attribute__((address_space(1))) void*)g,
                                   (__attribute__((address_space(3))) void*)l, 16, 0, 0);
}
__device__ __forceinline__ void store_out(float* p, float v) { *p = v; }
__device__ __forceinline__ void store_out(ushort* p, float v) { *p = f2bf(v); }

// ---------- fp32 -> bf16 cast ----------
__global__ __launch_bounds__(256) void cast_kernel(const float* __restrict__ in,
                                                   ushort* __restrict__ out, int n4) {
  int i = blockIdx.x * 256 + threadIdx.x;
  if (i < n4) {
    float4 v = ((const float4*)in)[i];
    ushort4 o;
    o.x = f2bf(v.x); o.y = f2bf(v.y); o.z = f2bf(v.z); o.w = f2bf(v.w);
    ((ushort4*)out)[i] = o;
  }
}

// ---------- NT GEMM: C[M,N] = A[M,K] * B[N,K]^T, bf16 in, fp32 acc ----------
// 128x128 tile, BK=64, 4 waves 2x2, each wave 2x2 of mfma_f32_32x32x16_bf16.
// K-tile stored as two k-half sub-arrays of 64B rows: As[h2][row][chunk^((row>>1)&3)]
// -> bank = (row&1)*16 + chunk*4: every aligned 8-lane group covers all 32 banks
// (the round-2 pattern that measured SQ_LDS_BANK_CONFLICT == 0).
template <typename OutT>
__global__ __launch_bounds__(256) void gemm_bt(const ushort* __restrict__ A,
                                               const ushort* __restrict__ B,
                                               OutT* __restrict__ C,
                                               int M, int N, int K) {
  __shared__ ushort As[2][128][32];
  __shared__ ushort Bs[2][128][32];
  const int tid = threadIdx.x;
  const int wave = tid >> 6, lane = tid & 63;
  const int half = lane >> 5, l32 = lane & 31;
  const int m0 = blockIdx.y * 128, n0 = blockIdx.x * 128;
  const int wr = wave >> 1, wc = wave & 1;
  // staging: 16 rows / instr; lane -> row lane>>2, chunk slot lane&3 (linear LDS),
  // source chunk XOR-swizzled so LDS[h2][r][c] = G[r][k0+h2*32+(c^((r>>1)&3))*8..]
  const int srow = lane >> 2;
  const int scol = ((lane & 3) ^ ((srow >> 1) & 3)) * 8;

  f32x16 acc[2][2] = {};

  for (int k0 = 0; k0 < K; k0 += 64) {
    __syncthreads();
#pragma unroll
    for (int h2 = 0; h2 < 2; ++h2)
#pragma unroll
      for (int p = 0; p < 2; ++p) {
        const int rg = wave * 32 + p * 16;
        load_lds16(A + (size_t)(m0 + rg + srow) * K + k0 + h2 * 32 + scol, &As[h2][rg][0]);
        load_lds16(B + (size_t)(n0 + rg + srow) * K + k0 + h2 * 32 + scol, &Bs[h2][rg][0]);
      }
    __syncthreads();
#pragma unroll
    for (int s = 0; s < 4; ++s) {
      const int h2 = s >> 1;
      const int cbase = (s & 1) * 2 + half;
      bf16x8 af[2], bfr[2];
#pragma unroll
      for (int i = 0; i < 2; ++i) {
        const int row = wr * 64 + i * 32 + l32;
        af[i] = *(const bf16x8*)(&As[h2][row][(cbase ^ ((row >> 1) & 3)) * 8]);
      }
#pragma unroll
      for (int j = 0; j < 2; ++j) {
        const int row = wc * 64 + j * 32 + l32;
        bfr[j] = *(const bf16x8*)(&Bs[h2][row][(cbase ^ ((row >> 1) & 3)) * 8]);
      }
#pragma unroll
      for (int i = 0; i < 2; ++i)
#pragma unroll
        for (int j = 0; j < 2; ++j)
          acc[i][j] = __builtin_amdgcn_mfma_f32_32x32x16_bf16(af[i], bfr[j], acc[i][j], 0, 0, 0);
    }
  }
  // epilogue: C/D layout col=lane&31, row=(reg&3)+8*(reg>>2)+4*(lane>>5) (m74/m101)
#pragma unroll
  for (int i = 0; i < 2; ++i)
#pragma unroll
    for (int j = 0; j < 2; ++j)
#pragma unroll
      for (int r = 0; r < 16; ++r) {
        const int row = m0 + wr * 64 + i * 32 + (r & 3) + 8 * (r >> 2) + 4 * half;
        const int col = n0 + wc * 64 + j * 32 + l32;
        store_out(C + (size_t)row * N + col, acc[i][j][r]);
      }
}

// ---------- RoPE in-place on bf16 qkv ----------
__global__ __launch_bounds__(256) void rope_kernel(const int* __restrict__ pos,
                                                   ushort* __restrict__ qkv) {
  const int rid = blockIdx.x * 4 + (threadIdx.x >> 6);
  const int d = threadIdx.x & 63;
  const int t = rid / 40;
  const int hh = rid - t * 40;
  ushort* p = qkv + (size_t)t * 6144 + (hh < 32 ? hh * 128 : 4096 + (hh - 32) * 128);
  const float inv_freq = powf(10000.0f, -(float)d * (1.0f / 64.0f));
  const float fr = (float)pos[t] * inv_freq;
  float sn, cs;
  sincosf(fr, &sn, &cs);
  const float x1 = bf2f(p[d]);
  const float x2 = bf2f(p[d + 64]);
  p[d] = f2bf(x1 * cs - x2 * sn);
  p[d + 64] = f2bf(x2 * cs + x1 * sn);
}

// ---------- fused flash attention (bf16 MFMA, causal GQA) ----------
// grid: 1024 = B(4) * H(32) * PAIR(8). Block = 256 thr = 4 waves.
// Block processes q-tiles (pair) and (15-pair) of 64 rows -> 17 k-tiles each.
__global__ __launch_bounds__(256) void attn_fused(const ushort* __restrict__ qkv,
                                                  ushort* __restrict__ outb) {
  const int bid = blockIdx.x;
  const int pair = bid & 7;
  const int h = (bid >> 3) & 31;
  const int b = bid >> 8;
  const int kvh = h >> 2;                  // G = 4
  const int tid = threadIdx.x, wave = tid >> 6, lane = tid & 63;
  const int quad = lane >> 4, lx = lane & 15;

  __shared__ ushort Ks[64 * 128];   // [key][d], chunk ^= key&7
  __shared__ ushort Vt[128 * 64];   // [d][key], chunk ^= d&7
  __shared__ ushort Ps[64 * 64];    // [qrow][key], chunk ^= qrow&7

  const size_t tb = (size_t)b * 1024;
  const float scale = 0.08838834764831843f;  // 1/sqrt(128)

#pragma unroll
  for (int phase = 0; phase < 2; ++phase) {
    const int qt64 = phase ? (15 - pair) : pair;
    const int qrow0 = qt64 * 64 + wave * 16;

    bf16x8 qf[4];
#pragma unroll
    for (int ks = 0; ks < 4; ++ks)
      qf[ks] = *(const bf16x8*)(qkv + (tb + qrow0 + lx) * 6144 + h * 128 + ks * 32 + quad * 8);

    f32x4 o[8] = {};
    float mst[4], lst[4];
#pragma unroll
    for (int r = 0; r < 4; ++r) { mst[r] = -1e30f; lst[r] = 0.f; }

    const int nkt = qt64 + 1;
    for (int it = 0; it < nkt; ++it) {
      const int kb = it * 64;
      __syncthreads();
#pragma unroll
      for (int i = 0; i < 4; ++i) {
        const int rg = wave * 16 + i * 4;
        const int row = rg + quad;
        load_lds16(qkv + (tb + kb + row) * 6144 + 4096 + kvh * 128 + ((lx ^ (row & 7)) * 8),
                   Ks + rg * 128);
      }
      {
        const ushort* vp = qkv + (tb + kb + lane) * 6144 + 5120 + kvh * 128 + wave * 32;
#pragma unroll
        for (int c = 0; c < 4; ++c) {
          bf16x8 v8 = *(const bf16x8*)(vp + c * 8);
#pragma unroll
          for (int e = 0; e < 8; ++e) {
            const int d = wave * 32 + c * 8 + e;
            Vt[d * 64 + (((lane >> 3) ^ (d & 7)) * 8) + (lane & 7)] = (ushort)v8[e];
          }
        }
      }
      __syncthreads();

      f32x4 s[4] = {};
#pragma unroll
      for (int ks = 0; ks < 4; ++ks) {
        bf16x8 kf[4];
#pragma unroll
        for (int kt = 0; kt < 4; ++kt)
          kf[kt] = *(const bf16x8*)(Ks + (kt * 16 + lx) * 128 + (((ks * 4 + quad) ^ (lx & 7)) * 8));
#pragma unroll
        for (int kt = 0; kt < 4; ++kt)
          s[kt] = __builtin_amdgcn_mfma_f32_16x16x32_bf16(qf[ks], kf[kt], s[kt], 0, 0, 0);
      }

      const bool diag = (kb + 63 > qrow0);
#pragma unroll
      for (int r = 0; r < 4; ++r) {
        const int row = qrow0 + quad * 4 + r;
        float mx = -1e30f;
#pragma unroll
        for (int kt = 0; kt < 4; ++kt) {
          float sv = s[kt][r] * scale;
          if (diag && (kb + kt * 16 + lx > row)) sv = -1e30f;
          s[kt][r] = sv;
          mx = fmaxf(mx, sv);
        }
        mx = fmaxf(mx, __shfl_xor(mx, 1));
        mx = fmaxf(mx, __shfl_xor(mx, 2));
        mx = fmaxf(mx, __shfl_xor(mx, 4));
        mx = fmaxf(mx, __shfl_xor(mx, 8));
        const float mnew = fmaxf(mst[r], mx);
        const float alpha = __expf(mst[r] - mnew);
        mst[r] = mnew;
        float rs = 0.f;
#pragma unroll
        for (int kt = 0; kt < 4; ++kt) {
          const float pv = __expf(s[kt][r] - mnew);
          s[kt][r] = pv;
          rs += pv;
        }
        rs += __shfl_xor(rs, 1); rs += __shfl_xor(rs, 2);
        rs += __shfl_xor(rs, 4); rs += __shfl_xor(rs, 8);
        lst[r] = lst[r] * alpha + rs;
#pragma unroll
        for (int dt = 0; dt < 8; ++dt) o[dt][r] *= alpha;
        const int prow = wave * 16 + quad * 4 + r;
#pragma unroll
        for (int kt = 0; kt < 4; ++kt)
          Ps[prow * 64 + (((kt * 2 + (lx >> 3)) ^ (prow & 7)) * 8) + (lx & 7)] = f2bf(s[kt][r]);
      }
      __syncthreads();

#pragma unroll
      for (int ks2 = 0; ks2 < 2; ++ks2) {
        const int prow = wave * 16 + lx;
        bf16x8 pf = *(const bf16x8*)(Ps + prow * 64 + (((ks2 * 4 + quad) ^ (lx & 7)) * 8));
#pragma unroll
        for (int dt = 0; dt < 8; ++dt) {
          bf16x8 vf = *(const bf16x8*)(Vt + (dt * 16 + lx) * 64 + (((ks2 * 4 + quad) ^ (lx & 7)) * 8));
          o[dt] = __builtin_amdgcn_mfma_f32_16x16x32_bf16(pf, vf, o[dt], 0, 0, 0);
        }
      }
    }

#pragma unroll
    for (int r = 0; r < 4; ++r) {
      const float inv = 1.f / lst[r];
      const int row = qrow0 + quad * 4 + r;
#pragma unroll
      for (int dt = 0; dt < 8; ++dt)
        outb[(tb + row) * 4096 + h * 128 + dt * 16 + lx] = f2bf(o[dt][r] * inv);
    }
  }
}

// ---------- launch ----------
extern "C" void kernel_launch(void* const* d_in, const int* in_sizes, int n_in,
                              void* d_out, int out_size, void* d_ws, size_t ws_size,
                              hipStream_t stream) {
  const int* positions = (const int*)d_in[0];
  const float* hidden  = (const float*)d_in[1];
  const float* w_qkv   = (const float*)d_in[2];
  const float* w_dense = (const float*)d_in[3];
  float* out = (float*)d_out;

  ushort* hidden_bf = (ushort*)d_ws;                         // 4096*4096
  ushort* wqkv_bf   = hidden_bf + (size_t)16777216;          // 6144*4096
  ushort* wdense_bf = wqkv_bf   + (size_t)25165824;          // 4096*4096
  ushort* qkv_bf    = wdense_bf + (size_t)16777216;          // 4096*6144
  ushort* attn_bf   = qkv_bf    + (size_t)25165824;          // 4096*4096

  cast_kernel<<<16384, 256, 0, stream>>>(hidden,  hidden_bf, 4194304);
  cast_kernel<<<24576, 256, 0, stream>>>(w_qkv,   wqkv_bf,   6291456);
  cast_kernel<<<16384, 256, 0, stream>>>(w_dense, wdense_bf, 4194304);

  gemm_bt<ushort><<<dim3(48, 32), 256, 0, stream>>>(hidden_bf, wqkv_bf, qkv_bf, 4096, 6144, 4096);

  rope_kernel<<<40960, 256, 0, stream>>>(positions, qkv_bf);

  attn_fused<<<1024, 256, 0, stream>>>(qkv_bf, attn_bf);

  gemm_bt<float><<<dim3(32, 32), 256, 0, stream>>>(attn_bf, wdense_bf, out, 4096, 4096, 4096);
}